// Round 6
// baseline (343.941 us; speedup 1.0000x reference)
//
#include <hip/hip_runtime.h>
#include <stdint.h>

#define NB 32
#define C_ 128
#define H_ 56
#define W_ 56
#define HW 3136
#define KD 384

typedef __attribute__((ext_vector_type(8))) short bf16x8;
typedef __attribute__((ext_vector_type(4))) float f32x4;

__device__ inline uint16_t f2bf(float f) {
    uint32_t u = __float_as_uint(f);
    return (uint16_t)((u + 0x7FFFu + ((u >> 16) & 1u)) >> 16);
}
__device__ inline float bf2f(uint16_t b) {
    return __uint_as_float(((uint32_t)b) << 16);
}

// ---------------------------------------------------------------------------
// P1: x (f32) -> xtp bf16 [n][h][w(64,pad0)][c]   (transposed for K1 B-operand)
// ---------------------------------------------------------------------------
__global__ __launch_bounds__(256) void p1_xtp(const float* __restrict__ x,
                                              uint16_t* __restrict__ xtp) {
    __shared__ uint16_t lt[56][136];
    const int h = blockIdx.x, n = blockIdx.y, tid = threadIdx.x;
    const int c = tid >> 1, wh = tid & 1;
    const float* xr = &x[(((size_t)n * C_ + c) * H_ + h) * W_ + wh * 28];
#pragma unroll
    for (int q = 0; q < 7; ++q) {
        float4 v = *(const float4*)&xr[q * 4];
        int wb = wh * 28 + q * 4;
        lt[wb + 0][c] = f2bf(v.x);
        lt[wb + 1][c] = f2bf(v.y);
        lt[wb + 2][c] = f2bf(v.z);
        lt[wb + 3][c] = f2bf(v.w);
    }
    __syncthreads();
    const int w = tid >> 2, qc = tid & 3;   // each thread owns 32 halves
    uint16_t* dst = &xtp[((((size_t)n * H_ + h) * 64 + w)) * C_ + qc * 32];
    if (w < 56) {
        const uint32_t* s = (const uint32_t*)&lt[w][qc * 32];
        uint4 a = *(const uint4*)(s);
        uint4 b = *(const uint4*)(s + 4);
        uint4 c4 = *(const uint4*)(s + 8);
        uint4 d4 = *(const uint4*)(s + 12);
        *(uint4*)dst = a;
        *(uint4*)(dst + 8) = b;
        *(uint4*)(dst + 16) = c4;
        *(uint4*)(dst + 24) = d4;
    } else {
        uint4 z = {0, 0, 0, 0};
        *(uint4*)dst = z;
        *(uint4*)(dst + 8) = z;
        *(uint4*)(dst + 16) = z;
        *(uint4*)(dst + 24) = z;
    }
}

// ---------------------------------------------------------------------------
// P2: p3 (f32 [c][3c2+tap]) -> ap bf16 [c][d'] with d' = tap*128 + c2
// ---------------------------------------------------------------------------
__global__ __launch_bounds__(256) void p2_ap(const float* __restrict__ p3,
                                             uint16_t* __restrict__ ap) {
    int i = blockIdx.x * 256 + threadIdx.x;  // < 49152
    int c = i / KD, dp = i - c * KD;
    int tap = dp >> 7, c2 = dp & 127;
    ap[i] = f2bf(p3[c * KD + 3 * c2 + tap]);
}

// ---------------------------------------------------------------------------
// K1: t3[c][w] = sum_{d'} ap[c][d'] * xtp[n][h+2(tap-1)][w][c2]   (MFMA)
// writes bf16 t3b[n][c][h][w64] (w 56..63 zero)
// ---------------------------------------------------------------------------
__global__ __launch_bounds__(256) void k1(const uint16_t* __restrict__ xtp,
                                          const uint16_t* __restrict__ ap,
                                          uint16_t* __restrict__ t3b) {
    __shared__ uint16_t smem[3 * 64 * 128];  // 48 KB; reused as lrow[128][72]
    const int h = blockIdx.x, n = blockIdx.y, tid = threadIdx.x;
    const int lane = tid & 63, wid = tid >> 6;
    const int wm = wid >> 1, wn = wid & 1;

    // stage B: 3 taps x 64 w-rows x 16 chunks (chunk-XOR swizzled, 256B rows)
    for (int t = tid; t < 3072; t += 256) {
        int tap = t >> 10, r = t & 1023, w = r >> 4, qp = r & 15;
        int q = qp ^ (w & 7);
        int hh = h + 2 * (tap - 1);
        uint4 v = {0, 0, 0, 0};
        if ((unsigned)hh < (unsigned)H_)
            v = *(const uint4*)&xtp[((((size_t)n * H_ + hh) * 64 + w)) * C_ + q * 8];
        *(uint4*)&smem[tap * 8192 + w * 128 + qp * 8] = v;
    }
    __syncthreads();

    f32x4 acc[4][2] = {};
    for (int ks = 0; ks < 12; ++ks) {
        int tap = ks >> 2, kk = ks & 3;
        bf16x8 a[4], b[2];
#pragma unroll
        for (int m = 0; m < 4; ++m) {
            int c = wm * 64 + m * 16 + (lane & 15);
            a[m] = *(const bf16x8*)&ap[c * KD + ks * 32 + (lane >> 4) * 8];
        }
#pragma unroll
        for (int nt = 0; nt < 2; ++nt) {
            int w = wn * 32 + nt * 16 + (lane & 15);
            int q = kk * 4 + (lane >> 4);
            b[nt] = *(const bf16x8*)&smem[tap * 8192 + w * 128 + (q ^ (w & 7)) * 8];
        }
#pragma unroll
        for (int m = 0; m < 4; ++m)
#pragma unroll
            for (int nt = 0; nt < 2; ++nt)
                acc[m][nt] = __builtin_amdgcn_mfma_f32_16x16x32_bf16(a[m], b[nt], acc[m][nt], 0, 0, 0);
    }
    __syncthreads();

    // acc -> lrow[128][72] bf16 (col = w), then linear uint4 stores
    uint16_t* lrow = smem;
#pragma unroll
    for (int m = 0; m < 4; ++m)
#pragma unroll
        for (int nt = 0; nt < 2; ++nt)
#pragma unroll
            for (int r = 0; r < 4; ++r) {
                int c = wm * 64 + m * 16 + (lane >> 4) * 4 + r;
                int w = wn * 32 + nt * 16 + (lane & 15);
                lrow[c * 72 + w] = f2bf(acc[m][nt][r]);
            }
    __syncthreads();

    const uint32_t* lrowd = (const uint32_t*)smem;
    for (int t = tid; t < 1024; t += 256) {
        int c = t >> 3, ch = t & 7;
        int m0 = c * 36 + ch * 4;
        uint4 o = make_uint4(lrowd[m0], lrowd[m0 + 1], lrowd[m0 + 2], lrowd[m0 + 3]);
        *(uint4*)&t3b[(((size_t)n * C_ + c) * H_ + h) * 64 + ch * 8] = o;
    }
}

// ---------------------------------------------------------------------------
// K2: part[bx][n][c][c2] = sum_{h in chunk, w} x[c][w] * t3[c2][w + tap-1]
// bx = hc*3 + tap; NO atomics (plain stores, reduced in kr).
// ---------------------------------------------------------------------------
__global__ __launch_bounds__(512) void k2(const float* __restrict__ x,
                                          const uint16_t* __restrict__ t3b,
                                          float* __restrict__ part) {
    __shared__ uint16_t xs[128 * 64];
    __shared__ uint16_t ts[128 * 64];
    const int bx = blockIdx.x;
    const int hc = bx / 3, tap = bx - hc * 3;
    const int n = blockIdx.y;
    const int tid = threadIdx.x, lane = tid & 63, wid = tid >> 6;
    const int wm = wid >> 2, wn = wid & 3;

    f32x4 acc[4][2] = {};
    for (int hr = 0; hr < 8; ++hr) {
        const int h = hc * 8 + hr;
        __syncthreads();
        for (int t = tid; t < 1024; t += 512) {
            int c = t >> 3, qp = t & 7, q = qp ^ (c & 7);
            uint4 v = {0, 0, 0, 0};
            if (q < 7) {
                const float* s = &x[(((size_t)n * C_ + c) * H_ + h) * W_ + q * 8];
                float4 f0 = *(const float4*)s, f1 = *(const float4*)(s + 4);
                v.x = (uint32_t)f2bf(f0.x) | ((uint32_t)f2bf(f0.y) << 16);
                v.y = (uint32_t)f2bf(f0.z) | ((uint32_t)f2bf(f0.w) << 16);
                v.z = (uint32_t)f2bf(f1.x) | ((uint32_t)f2bf(f1.y) << 16);
                v.w = (uint32_t)f2bf(f1.z) | ((uint32_t)f2bf(f1.w) << 16);
            }
            *(uint4*)&xs[c * 64 + qp * 8] = v;
        }
        for (int t = tid; t < 1024; t += 512) {
            int c2 = t >> 3, qp = t & 7, q = qp ^ (c2 & 7);
            const uint16_t* row = &t3b[(((size_t)n * C_ + c2) * H_ + h) * 64];
            uint4 v = *(const uint4*)&row[q * 8];
            uint4 o;
            if (tap == 1) {
                o = v;
            } else if (tap == 2) {  // want t3[w+1]
                uint32_t nx = (q < 7) ? *(const uint32_t*)&row[q * 8 + 8] : 0u;
                o.x = (v.y << 16) | (v.x >> 16);
                o.y = (v.z << 16) | (v.y >> 16);
                o.z = (v.w << 16) | (v.z >> 16);
                o.w = (nx << 16)  | (v.w >> 16);
            } else {                // tap 0: want t3[w-1]
                uint32_t pv = (q > 0) ? *(const uint32_t*)&row[q * 8 - 2] : 0u;
                o.x = (v.x << 16) | (pv >> 16);
                o.y = (v.y << 16) | (v.x >> 16);
                o.z = (v.z << 16) | (v.y >> 16);
                o.w = (v.w << 16) | (v.z >> 16);
            }
            *(uint4*)&ts[c2 * 64 + qp * 8] = o;
        }
        __syncthreads();
#pragma unroll
        for (int ks = 0; ks < 2; ++ks) {
            bf16x8 a[4], b[2];
#pragma unroll
            for (int m = 0; m < 4; ++m) {
                int c = wm * 64 + m * 16 + (lane & 15);
                int q = ks * 4 + (lane >> 4);
                a[m] = *(const bf16x8*)&xs[c * 64 + (q ^ (c & 7)) * 8];
            }
#pragma unroll
            for (int nt = 0; nt < 2; ++nt) {
                int c2 = wn * 32 + nt * 16 + (lane & 15);
                int q = ks * 4 + (lane >> 4);
                b[nt] = *(const bf16x8*)&ts[c2 * 64 + (q ^ (c2 & 7)) * 8];
            }
#pragma unroll
            for (int m = 0; m < 4; ++m)
#pragma unroll
                for (int nt = 0; nt < 2; ++nt)
                    acc[m][nt] = __builtin_amdgcn_mfma_f32_16x16x32_bf16(a[m], b[nt], acc[m][nt], 0, 0, 0);
        }
    }
#pragma unroll
    for (int m = 0; m < 4; ++m)
#pragma unroll
        for (int nt = 0; nt < 2; ++nt)
#pragma unroll
            for (int r = 0; r < 4; ++r) {
                int c = wm * 64 + m * 16 + (lane >> 4) * 4 + r;
                int col = wn * 32 + nt * 16 + (lane & 15);
                part[((((size_t)bx * NB + n) * C_ + c) << 7) + col] = acc[m][nt][r];
            }
}

// ---------------------------------------------------------------------------
// R: t9rb[n][c][tap*128+c2] = bf16( (1/56) * sum_hc part[hc*3+tap][n][c][c2] )
// ---------------------------------------------------------------------------
__global__ __launch_bounds__(256) void kr(const float* __restrict__ part,
                                          uint16_t* __restrict__ t9rb) {
    int idx = blockIdx.x * 256 + threadIdx.x;   // 393216 threads, 4 elems each
    int fl = idx * 4;
    int nc = fl / KD, dp = fl - nc * KD;
    int tap = dp >> 7, c2 = dp & 127;
    float4 s = make_float4(0.f, 0.f, 0.f, 0.f);
#pragma unroll
    for (int hc = 0; hc < 7; ++hc) {
        const float4 v = *(const float4*)&part[((((size_t)(hc * 3 + tap)) * NB * C_ + nc) << 7) + c2];
        s.x += v.x; s.y += v.y; s.z += v.z; s.w += v.w;
    }
    const float sc = 1.f / 56.f;
    uint2 o;
    o.x = (uint32_t)f2bf(s.x * sc) | ((uint32_t)f2bf(s.y * sc) << 16);
    o.y = (uint32_t)f2bf(s.z * sc) | ((uint32_t)f2bf(s.w * sc) << 16);
    *(uint2*)&t9rb[fl] = o;
}

// ---------------------------------------------------------------------------
// KB: t12 build, zero-LDS streaming kernel (high occupancy for latency hiding).
// Writes t12b[n][hb][w64][d'=384] bf16, UNswizzled; pad rows w>=56 are zeros.
// h = hb*2 + hpar (h-parity split so t12b fits 44MB aliasing `part`).
// ---------------------------------------------------------------------------
__global__ __launch_bounds__(256) void kb(const float* __restrict__ x,
                                          const uint16_t* __restrict__ t3b,
                                          const float* __restrict__ p2,
                                          const float* __restrict__ p5,
                                          const float* __restrict__ p10,
                                          uint16_t* __restrict__ t12b, int hpar) {
    const int n = blockIdx.x, hb = blockIdx.y;
    const int h = hb * 2 + hpar;
    const int tid = threadIdx.x, lane = tid & 63, wid = tid >> 6;
    const int w = lane;
    const bool valid = (w < 56);
    const float p5v = valid ? p5[h * W_ + w] : 0.f;
    float p2v[3];
#pragma unroll
    for (int tap = 0; tap < 3; ++tap) p2v[tap] = valid ? p2[tap * W_ + w] : 0.f;
    uint16_t* tile = &t12b[((size_t)n * 28 + hb) * 24576];

#pragma unroll 2
    for (int cc = 0; cc < 4; ++cc) {
        const int c2b = (wid * 4 + cc) * 8;
        float xc[8], sm0[8], sm1[8], sm2[8];
#pragma unroll
        for (int j = 0; j < 8; ++j) {
            int c2 = c2b + j;
            float a1 = valid ? x[(((size_t)n * C_ + c2) * H_ + h) * W_ + w] : 0.f;
            xc[j] = a1;
            float a0 = __shfl_up(a1, 2);
            if (w < 2) a0 = 0.f;
            float a2 = __shfl_down(a1, 2);
            if (w >= 54) a2 = 0.f;      // lanes 54,55: neighbor is w>=56 (zero); >=62: avoid UB
            float mx = fmaxf(a0, fmaxf(a1, a2));
            float e0 = __expf(a0 - mx), e1 = __expf(a1 - mx), e2 = __expf(a2 - mx);
            float rs = 1.f / (e0 + e1 + e2);
            sm0[j] = e0 * rs; sm1[j] = e1 * rs; sm2[j] = e2 * rs;
        }
#pragma unroll
        for (int tap = 0; tap < 3; ++tap) {
            const int hh = h + 2 * (tap - 1);
            const bool hok = (unsigned)hh < (unsigned)H_;
            uint32_t pk[4];
#pragma unroll
            for (int j = 0; j < 8; ++j) {
                int c2 = c2b + j;
                float xh = (tap == 1) ? xc[j]
                                      : ((hok && valid) ? x[(((size_t)n * C_ + c2) * H_ + hh) * W_ + w] : 0.f);
                int dor = 3 * c2 + tap;
                float t3v = valid ? bf2f(t3b[(((size_t)n * C_ + (dor & 127)) * H_ + h) * 64 + w]) : 0.f;
                float p10v = valid ? p10[((size_t)dor * H_ + h) * W_ + w] : 0.f;
                float smv = (tap == 0) ? sm0[j] : (tap == 1 ? sm1[j] : sm2[j]);
                float val = p5v * t3v - p2v[tap] * xh - p10v * smv;  // = 0 for w>=56
                uint16_t bb = f2bf(val);
                if (j & 1) pk[j >> 1] |= ((uint32_t)bb) << 16;
                else       pk[j >> 1] = bb;
            }
            // unconditional store: fills pad rows w>=56 with zeros
            *(uint4*)&tile[w * 384 + tap * 128 + c2b] = *(const uint4*)pk;
        }
    }
}

// ---------------------------------------------------------------------------
// K3G: pure GEMM  out[c][w] = (1/sqrt384) sum_k t9rb[c][k] * t12b_tile[w][k]
// stage 48KB tile (coalesced uint4 reads -> XOR-swizzled ds_write), 12 ksteps.
// ---------------------------------------------------------------------------
__global__ __launch_bounds__(256) void k3g(const uint16_t* __restrict__ t12b,
                                           const uint16_t* __restrict__ t9rb,
                                           float* __restrict__ out, int hpar) {
    __shared__ uint16_t tsm[64 * 384];  // 48 KB
    const int n = blockIdx.x, hb = blockIdx.y;
    const int h = hb * 2 + hpar;
    const int tid = threadIdx.x, lane = tid & 63, wid = tid >> 6;
    const uint16_t* tile = &t12b[((size_t)n * 28 + hb) * 24576];

    // stage: 3072 16B-chunks; global linear (perfectly coalesced), LDS swizzled
#pragma unroll
    for (int r = 0; r < 12; ++r) {
        int idx = r * 256 + tid;            // 0..3071
        int w = idx / 48, q = idx - w * 48; // 48 chunks per 768B row
        uint4 v = *(const uint4*)&tile[idx * 8];
        *(uint4*)&tsm[w * 384 + (q ^ (w & 7)) * 8] = v;
    }
    __syncthreads();

    const int wm = wid >> 1, wn = wid & 1;
    f32x4 acc[4][2] = {};
    for (int ks = 0; ks < 12; ++ks) {
        bf16x8 a[4], b[2];
#pragma unroll
        for (int m = 0; m < 4; ++m) {
            int c = wm * 64 + m * 16 + (lane & 15);
            a[m] = *(const bf16x8*)&t9rb[((size_t)n * C_ + c) * KD + ks * 32 + (lane >> 4) * 8];
        }
#pragma unroll
        for (int nt = 0; nt < 2; ++nt) {
            int ww = wn * 32 + nt * 16 + (lane & 15);
            int k0 = ks * 32 + (lane >> 4) * 8;
            b[nt] = *(const bf16x8*)&tsm[ww * 384 + (k0 ^ ((ww & 7) << 3))];
        }
#pragma unroll
        for (int m = 0; m < 4; ++m)
#pragma unroll
            for (int nt = 0; nt < 2; ++nt)
                acc[m][nt] = __builtin_amdgcn_mfma_f32_16x16x32_bf16(a[m], b[nt], acc[m][nt], 0, 0, 0);
    }

    const float s = 0.05103103630798287f;  // 1/sqrt(384)
#pragma unroll
    for (int m = 0; m < 4; ++m)
#pragma unroll
        for (int nt = 0; nt < 2; ++nt) {
            int ww = wn * 32 + nt * 16 + (lane & 15);
            if (ww < 56) {
                int c = wm * 64 + m * 16 + (lane >> 4) * 4;
                float* dst = &out[(((size_t)n * C_ + c) * H_ + h) * W_ + ww];
#pragma unroll
                for (int r = 0; r < 4; ++r) dst[(size_t)r * HW] = acc[m][nt][r] * s;
            }
        }
}

extern "C" void kernel_launch(void* const* d_in, const int* in_sizes, int n_in,
                              void* d_out, int out_size, void* d_ws, size_t ws_size,
                              hipStream_t stream) {
    const float* x   = (const float*)d_in[0];
    const float* p2  = (const float*)d_in[1];
    const float* p3  = (const float*)d_in[2];
    const float* p5  = (const float*)d_in[3];
    const float* p10 = (const float*)d_in[4];
    float* out = (float*)d_out;

    uint8_t* w8 = (uint8_t*)d_ws;
    uint16_t* t3b  = (uint16_t*)(w8);                 // 29,360,128 B (live to end)
    uint16_t* ap   = (uint16_t*)(w8 + 29360128);      //     98,304 B
    uint16_t* xtp  = (uint16_t*)(w8 + 29458432);      // 29,360,128 B (dead after k1)
    uint16_t* t9rb = (uint16_t*)(w8 + 29458432);      //  3,145,728 B (aliases dead xtp)
    float*    part = (float*)   (w8 + 58818560);      // 44,040,192 B (dead after kr)
    uint16_t* t12b = (uint16_t*)(w8 + 58818560);      // 44,040,192 B (aliases dead part)
    // total ws footprint: 102,858,752 B (same as rounds 3-5)

    p1_xtp<<<dim3(H_, NB), 256, 0, stream>>>(x, xtp);
    p2_ap<<<dim3(192), 256, 0, stream>>>(p3, ap);
    k1<<<dim3(H_, NB), 256, 0, stream>>>(xtp, ap, t3b);
    k2<<<dim3(21, NB), 512, 0, stream>>>(x, t3b, part);
    kr<<<dim3(1536), 256, 0, stream>>>(part, t9rb);
    kb<<<dim3(NB, 28), 256, 0, stream>>>(x, t3b, p2, p5, p10, t12b, 0);
    k3g<<<dim3(NB, 28), 256, 0, stream>>>(t12b, t9rb, out, 0);
    kb<<<dim3(NB, 28), 256, 0, stream>>>(x, t3b, p2, p5, p10, t12b, 1);
    k3g<<<dim3(NB, 28), 256, 0, stream>>>(t12b, t9rb, out, 1);
}

// Round 7
// 262.027 us; speedup vs baseline: 1.3126x; 1.3126x over previous
//
#include <hip/hip_runtime.h>
#include <stdint.h>

#define NB 32
#define C_ 128
#define H_ 56
#define W_ 56
#define HW 3136
#define KD 384

typedef __attribute__((ext_vector_type(8))) short bf16x8;
typedef __attribute__((ext_vector_type(4))) float f32x4;

__device__ inline uint16_t f2bf(float f) {
    uint32_t u = __float_as_uint(f);
    return (uint16_t)((u + 0x7FFFu + ((u >> 16) & 1u)) >> 16);
}
__device__ inline float bf2f(uint16_t b) {
    return __uint_as_float(((uint32_t)b) << 16);
}

// ---------------------------------------------------------------------------
// P1: x (f32) -> xtp bf16 [n][h][w(64,pad0)][c]
// ---------------------------------------------------------------------------
__global__ __launch_bounds__(256) void p1_xtp(const float* __restrict__ x,
                                              uint16_t* __restrict__ xtp) {
    __shared__ uint16_t lt[56][136];
    const int h = blockIdx.x, n = blockIdx.y, tid = threadIdx.x;
    const int c = tid >> 1, wh = tid & 1;
    const float* xr = &x[(((size_t)n * C_ + c) * H_ + h) * W_ + wh * 28];
#pragma unroll
    for (int q = 0; q < 7; ++q) {
        float4 v = *(const float4*)&xr[q * 4];
        int wb = wh * 28 + q * 4;
        lt[wb + 0][c] = f2bf(v.x);
        lt[wb + 1][c] = f2bf(v.y);
        lt[wb + 2][c] = f2bf(v.z);
        lt[wb + 3][c] = f2bf(v.w);
    }
    __syncthreads();
    const int w = tid >> 2, qc = tid & 3;
    uint16_t* dst = &xtp[((((size_t)n * H_ + h) * 64 + w)) * C_ + qc * 32];
    if (w < 56) {
        const uint32_t* s = (const uint32_t*)&lt[w][qc * 32];
        uint4 a = *(const uint4*)(s);
        uint4 b = *(const uint4*)(s + 4);
        uint4 c4 = *(const uint4*)(s + 8);
        uint4 d4 = *(const uint4*)(s + 12);
        *(uint4*)dst = a;
        *(uint4*)(dst + 8) = b;
        *(uint4*)(dst + 16) = c4;
        *(uint4*)(dst + 24) = d4;
    } else {
        uint4 z = {0, 0, 0, 0};
        *(uint4*)dst = z;
        *(uint4*)(dst + 8) = z;
        *(uint4*)(dst + 16) = z;
        *(uint4*)(dst + 24) = z;
    }
}

// ---------------------------------------------------------------------------
// P2: p3 -> ap bf16 [c][d'=tap*128+c2]
// ---------------------------------------------------------------------------
__global__ __launch_bounds__(256) void p2_ap(const float* __restrict__ p3,
                                             uint16_t* __restrict__ ap) {
    int i = blockIdx.x * 256 + threadIdx.x;
    int c = i / KD, dp = i - c * KD;
    int tap = dp >> 7, c2 = dp & 127;
    ap[i] = f2bf(p3[c * KD + 3 * c2 + tap]);
}

// ---------------------------------------------------------------------------
// K1: MFMA -> t3b[n][c][h][w64]
// ---------------------------------------------------------------------------
__global__ __launch_bounds__(256) void k1(const uint16_t* __restrict__ xtp,
                                          const uint16_t* __restrict__ ap,
                                          uint16_t* __restrict__ t3b) {
    __shared__ uint16_t smem[3 * 64 * 128];
    const int h = blockIdx.x, n = blockIdx.y, tid = threadIdx.x;
    const int lane = tid & 63, wid = tid >> 6;
    const int wm = wid >> 1, wn = wid & 1;

    for (int t = tid; t < 3072; t += 256) {
        int tap = t >> 10, r = t & 1023, w = r >> 4, qp = r & 15;
        int q = qp ^ (w & 7);
        int hh = h + 2 * (tap - 1);
        uint4 v = {0, 0, 0, 0};
        if ((unsigned)hh < (unsigned)H_)
            v = *(const uint4*)&xtp[((((size_t)n * H_ + hh) * 64 + w)) * C_ + q * 8];
        *(uint4*)&smem[tap * 8192 + w * 128 + qp * 8] = v;
    }
    __syncthreads();

    f32x4 acc[4][2] = {};
    for (int ks = 0; ks < 12; ++ks) {
        int tap = ks >> 2, kk = ks & 3;
        bf16x8 a[4], b[2];
#pragma unroll
        for (int m = 0; m < 4; ++m) {
            int c = wm * 64 + m * 16 + (lane & 15);
            a[m] = *(const bf16x8*)&ap[c * KD + ks * 32 + (lane >> 4) * 8];
        }
#pragma unroll
        for (int nt = 0; nt < 2; ++nt) {
            int w = wn * 32 + nt * 16 + (lane & 15);
            int q = kk * 4 + (lane >> 4);
            b[nt] = *(const bf16x8*)&smem[tap * 8192 + w * 128 + (q ^ (w & 7)) * 8];
        }
#pragma unroll
        for (int m = 0; m < 4; ++m)
#pragma unroll
            for (int nt = 0; nt < 2; ++nt)
                acc[m][nt] = __builtin_amdgcn_mfma_f32_16x16x32_bf16(a[m], b[nt], acc[m][nt], 0, 0, 0);
    }
    __syncthreads();

    uint16_t* lrow = smem;
#pragma unroll
    for (int m = 0; m < 4; ++m)
#pragma unroll
        for (int nt = 0; nt < 2; ++nt)
#pragma unroll
            for (int r = 0; r < 4; ++r) {
                int c = wm * 64 + m * 16 + (lane >> 4) * 4 + r;
                int w = wn * 32 + nt * 16 + (lane & 15);
                lrow[c * 72 + w] = f2bf(acc[m][nt][r]);
            }
    __syncthreads();

    const uint32_t* lrowd = (const uint32_t*)smem;
    for (int t = tid; t < 1024; t += 256) {
        int c = t >> 3, ch = t & 7;
        int m0 = c * 36 + ch * 4;
        uint4 o = make_uint4(lrowd[m0], lrowd[m0 + 1], lrowd[m0 + 2], lrowd[m0 + 3]);
        *(uint4*)&t3b[(((size_t)n * C_ + c) * H_ + h) * 64 + ch * 8] = o;
    }
}

// ---------------------------------------------------------------------------
// K2: part[bx][n][c][c2] partial t9 (plain stores, reduced in kr)
// ---------------------------------------------------------------------------
__global__ __launch_bounds__(512) void k2(const float* __restrict__ x,
                                          const uint16_t* __restrict__ t3b,
                                          float* __restrict__ part) {
    __shared__ uint16_t xs[128 * 64];
    __shared__ uint16_t ts[128 * 64];
    const int bx = blockIdx.x;
    const int hc = bx / 3, tap = bx - hc * 3;
    const int n = blockIdx.y;
    const int tid = threadIdx.x, lane = tid & 63, wid = tid >> 6;
    const int wm = wid >> 2, wn = wid & 3;

    f32x4 acc[4][2] = {};
    for (int hr = 0; hr < 8; ++hr) {
        const int h = hc * 8 + hr;
        __syncthreads();
        for (int t = tid; t < 1024; t += 512) {
            int c = t >> 3, qp = t & 7, q = qp ^ (c & 7);
            uint4 v = {0, 0, 0, 0};
            if (q < 7) {
                const float* s = &x[(((size_t)n * C_ + c) * H_ + h) * W_ + q * 8];
                float4 f0 = *(const float4*)s, f1 = *(const float4*)(s + 4);
                v.x = (uint32_t)f2bf(f0.x) | ((uint32_t)f2bf(f0.y) << 16);
                v.y = (uint32_t)f2bf(f0.z) | ((uint32_t)f2bf(f0.w) << 16);
                v.z = (uint32_t)f2bf(f1.x) | ((uint32_t)f2bf(f1.y) << 16);
                v.w = (uint32_t)f2bf(f1.z) | ((uint32_t)f2bf(f1.w) << 16);
            }
            *(uint4*)&xs[c * 64 + qp * 8] = v;
        }
        for (int t = tid; t < 1024; t += 512) {
            int c2 = t >> 3, qp = t & 7, q = qp ^ (c2 & 7);
            const uint16_t* row = &t3b[(((size_t)n * C_ + c2) * H_ + h) * 64];
            uint4 v = *(const uint4*)&row[q * 8];
            uint4 o;
            if (tap == 1) {
                o = v;
            } else if (tap == 2) {
                uint32_t nx = (q < 7) ? *(const uint32_t*)&row[q * 8 + 8] : 0u;
                o.x = (v.y << 16) | (v.x >> 16);
                o.y = (v.z << 16) | (v.y >> 16);
                o.z = (v.w << 16) | (v.z >> 16);
                o.w = (nx << 16)  | (v.w >> 16);
            } else {
                uint32_t pv = (q > 0) ? *(const uint32_t*)&row[q * 8 - 2] : 0u;
                o.x = (v.x << 16) | (pv >> 16);
                o.y = (v.y << 16) | (v.x >> 16);
                o.z = (v.z << 16) | (v.y >> 16);
                o.w = (v.w << 16) | (v.z >> 16);
            }
            *(uint4*)&ts[c2 * 64 + qp * 8] = o;
        }
        __syncthreads();
#pragma unroll
        for (int ks = 0; ks < 2; ++ks) {
            bf16x8 a[4], b[2];
#pragma unroll
            for (int m = 0; m < 4; ++m) {
                int c = wm * 64 + m * 16 + (lane & 15);
                int q = ks * 4 + (lane >> 4);
                a[m] = *(const bf16x8*)&xs[c * 64 + (q ^ (c & 7)) * 8];
            }
#pragma unroll
            for (int nt = 0; nt < 2; ++nt) {
                int c2 = wn * 32 + nt * 16 + (lane & 15);
                int q = ks * 4 + (lane >> 4);
                b[nt] = *(const bf16x8*)&ts[c2 * 64 + (q ^ (c2 & 7)) * 8];
            }
#pragma unroll
            for (int m = 0; m < 4; ++m)
#pragma unroll
                for (int nt = 0; nt < 2; ++nt)
                    acc[m][nt] = __builtin_amdgcn_mfma_f32_16x16x32_bf16(a[m], b[nt], acc[m][nt], 0, 0, 0);
        }
    }
#pragma unroll
    for (int m = 0; m < 4; ++m)
#pragma unroll
        for (int nt = 0; nt < 2; ++nt)
#pragma unroll
            for (int r = 0; r < 4; ++r) {
                int c = wm * 64 + m * 16 + (lane >> 4) * 4 + r;
                int col = wn * 32 + nt * 16 + (lane & 15);
                part[((((size_t)bx * NB + n) * C_ + c) << 7) + col] = acc[m][nt][r];
            }
}

// ---------------------------------------------------------------------------
// R: acat[n][c][dp<384] = bf16( (1/56) * sum_hc part )   (row stride 512!)
// ---------------------------------------------------------------------------
__global__ __launch_bounds__(256) void kr(const float* __restrict__ part,
                                          uint16_t* __restrict__ acat) {
    int idx = blockIdx.x * 256 + threadIdx.x;
    int fl = idx * 4;
    int nc = fl / KD, dp = fl - nc * KD;
    int tap = dp >> 7, c2 = dp & 127;
    float4 s = make_float4(0.f, 0.f, 0.f, 0.f);
#pragma unroll
    for (int hc = 0; hc < 7; ++hc) {
        const float4 v = *(const float4*)&part[((((size_t)(hc * 3 + tap)) * NB * C_ + nc) << 7) + c2];
        s.x += v.x; s.y += v.y; s.z += v.z; s.w += v.w;
    }
    const float sc = 1.f / 56.f;
    uint2 o;
    o.x = (uint32_t)f2bf(s.x * sc) | ((uint32_t)f2bf(s.y * sc) << 16);
    o.y = (uint32_t)f2bf(s.z * sc) | ((uint32_t)f2bf(s.w * sc) << 16);
    *(uint2*)&acat[(size_t)nc * 512 + dp] = o;
}

// ---------------------------------------------------------------------------
// KA2: acat[nc][384+m] = sum_{r=0..2} acat[nc][dp(m+128r)], dp(d)=(d%3)*128+d/3
// ---------------------------------------------------------------------------
__global__ __launch_bounds__(256) void ka2(uint16_t* __restrict__ acat) {
    int t = blockIdx.x * 256 + threadIdx.x;   // 32768 threads
    int nc = t >> 3, m0 = (t & 7) * 16;
    uint16_t* row = &acat[(size_t)nc * 512];
#pragma unroll
    for (int mi = 0; mi < 16; ++mi) {
        int m = m0 + mi;
        float s = 0.f;
#pragma unroll
        for (int r = 0; r < 3; ++r) {
            int d = m + 128 * r;
            int q3 = d / 3;
            int dp = (d - q3 * 3) * 128 + q3;
            s += bf2f(row[dp]);
        }
        row[384 + m] = f2bf(s);
    }
}

// ---------------------------------------------------------------------------
// KT: p10 -> p10t bf16 [h][w64][d'=tap*128+c2]; rows w>=56 zero
// ---------------------------------------------------------------------------
__global__ __launch_bounds__(256) void kt(const float* __restrict__ p10,
                                          uint16_t* __restrict__ p10t) {
    const int h = blockIdx.x, tid = threadIdx.x;
    for (int idx = tid; idx < 3072; idx += 256) {
        int w = idx & 63, ch = idx >> 6;     // ch: 0..47
        int dp0 = ch * 8;
        uint32_t pk[4];
#pragma unroll
        for (int j = 0; j < 8; ++j) {
            int dp = dp0 + j;
            int tap = dp >> 7, c2 = dp & 127;
            int dor = 3 * c2 + tap;
            float v = (w < W_) ? p10[(size_t)dor * HW + h * W_ + w] : 0.f;
            uint16_t bb = f2bf(v);
            if (j & 1) pk[j >> 1] |= ((uint32_t)bb) << 16;
            else       pk[j >> 1] = bb;
        }
        *(uint4*)&p10t[((size_t)h * 64 + w) * KD + dp0] = *(const uint4*)pk;
    }
}

// ---------------------------------------------------------------------------
// K3: single K=512 GEMM.  B rows 0..383 = -(p2*x + p10*sm) (vectorized build),
// rows 384..511 = p5*t3.  A = acat = [t9' | A2].  out = acc/sqrt(384).
// ---------------------------------------------------------------------------
__global__ __launch_bounds__(256) void k3(const uint16_t* __restrict__ xtp,
                                          const uint16_t* __restrict__ t3b,
                                          const uint16_t* __restrict__ acat,
                                          const uint16_t* __restrict__ p10t,
                                          const float* __restrict__ p2,
                                          const float* __restrict__ p5,
                                          float* __restrict__ out) {
    __shared__ uint16_t tsm[64 * 512];  // 64 KB, rows w (1024B), 64 chunks XOR-swz
    const int h = blockIdx.x, n = blockIdx.y, tid = threadIdx.x;
    const int lane = tid & 63, wid = tid >> 6;
    const int w = lane;
    const int wsw = w & 7;
    float p2v[3];
#pragma unroll
    for (int tap = 0; tap < 3; ++tap)
        p2v[tap] = (w < W_) ? p2[tap * W_ + w] : 0.f;

    const size_t xrow = ((size_t)n * H_ + h) * 64;
    const int wm2 = (w >= 2) ? w - 2 : 0;
    const int wp2 = (w + 2 < 64) ? w + 2 : 63;   // rows >=56 are zeros

    // ---- rows 0..383: lane = w, vectorized over 8 c2 per load ----
#pragma unroll
    for (int cc = 0; cc < 4; ++cc) {
        const int c2b = (wid * 4 + cc) * 8;
        bf16x8 xh_v = *(const bf16x8*)&xtp[(xrow + w) * C_ + c2b];
        bf16x8 xm_v = *(const bf16x8*)&xtp[(xrow + wm2) * C_ + c2b];
        bf16x8 xp_v = *(const bf16x8*)&xtp[(xrow + wp2) * C_ + c2b];
        float sm[3][8];
#pragma unroll
        for (int j = 0; j < 8; ++j) {
            float a1 = bf2f((uint16_t)xh_v[j]);
            float a0 = (w >= 2) ? bf2f((uint16_t)xm_v[j]) : 0.f;
            float a2 = bf2f((uint16_t)xp_v[j]);
            float mx = fmaxf(a0, fmaxf(a1, a2));
            float e0 = __expf(a0 - mx), e1 = __expf(a1 - mx), e2 = __expf(a2 - mx);
            float rs = 1.f / (e0 + e1 + e2);
            sm[0][j] = e0 * rs; sm[1][j] = e1 * rs; sm[2][j] = e2 * rs;
        }
#pragma unroll
        for (int tap = 0; tap < 3; ++tap) {
            bf16x8 xhh;
            float p2e;
            if (tap == 1) { xhh = xh_v; p2e = p2v[1]; }
            else {
                const int hh = h + 2 * (tap - 1);
                const bool hok = (unsigned)hh < (unsigned)H_;
                const int hhc = hok ? hh : h;
                xhh = *(const bf16x8*)&xtp[(((size_t)n * H_ + hhc) * 64 + w) * C_ + c2b];
                p2e = hok ? p2v[tap] : 0.f;
            }
            bf16x8 pv = *(const bf16x8*)&p10t[((size_t)h * 64 + w) * KD + tap * 128 + c2b];
            uint32_t pk[4];
#pragma unroll
            for (int j = 0; j < 8; ++j) {
                float val = -(p2e * bf2f((uint16_t)xhh[j]) + bf2f((uint16_t)pv[j]) * sm[tap][j]);
                uint16_t bb = f2bf(val);
                if (j & 1) pk[j >> 1] |= ((uint32_t)bb) << 16;
                else       pk[j >> 1] = bb;
            }
            int q = tap * 16 + (c2b >> 3);
            *(uint4*)&tsm[w * 512 + ((q ^ wsw) << 3)] = *(const uint4*)pk;
        }
    }

    // ---- rows 384..511: p5*t3, lane = c2 pair, scalar LDS writes ----
    {
        const int c2f = tid >> 1;
        const int whf = (tid & 1) << 5;
        const uint16_t* t3r = &t3b[(((size_t)n * C_ + c2f) * H_ + h) * 64 + whf];
        const int qf = 48 + (c2f >> 3);
        const int cf7 = c2f & 7;
#pragma unroll
        for (int g = 0; g < 4; ++g) {
            bf16x8 tv = *(const bf16x8*)&t3r[g * 8];
#pragma unroll
            for (int j = 0; j < 8; ++j) {
                int ww = whf + g * 8 + j;
                float p5v = (ww < W_) ? p5[h * W_ + ww] : 0.f;
                tsm[ww * 512 + ((qf ^ (ww & 7)) << 3) + cf7] = f2bf(p5v * bf2f((uint16_t)tv[j]));
            }
        }
    }
    __syncthreads();

    // ---- 16-kstep GEMM over K=512 ----
    const int wm = wid >> 1, wn = wid & 1;
    f32x4 acc[4][2] = {};
    for (int ks = 0; ks < 16; ++ks) {
        bf16x8 a[4], b[2];
#pragma unroll
        for (int m = 0; m < 4; ++m) {
            int c = wm * 64 + m * 16 + (lane & 15);
            a[m] = *(const bf16x8*)&acat[((size_t)n * C_ + c) * 512 + ks * 32 + (lane >> 4) * 8];
        }
#pragma unroll
        for (int nt = 0; nt < 2; ++nt) {
            int ww = wn * 32 + nt * 16 + (lane & 15);
            int q = ks * 4 + (lane >> 4);
            b[nt] = *(const bf16x8*)&tsm[ww * 512 + ((q ^ (ww & 7)) << 3)];
        }
#pragma unroll
        for (int m = 0; m < 4; ++m)
#pragma unroll
            for (int nt = 0; nt < 2; ++nt)
                acc[m][nt] = __builtin_amdgcn_mfma_f32_16x16x32_bf16(a[m], b[nt], acc[m][nt], 0, 0, 0);
    }

    const float s = 0.05103103630798287f;  // 1/sqrt(384)
#pragma unroll
    for (int m = 0; m < 4; ++m)
#pragma unroll
        for (int nt = 0; nt < 2; ++nt) {
            int ww = wn * 32 + nt * 16 + (lane & 15);
            if (ww < W_) {
                int c = wm * 64 + m * 16 + (lane >> 4) * 4;
                float* dst = &out[(((size_t)n * C_ + c) * H_ + h) * W_ + ww];
#pragma unroll
                for (int r = 0; r < 4; ++r) dst[(size_t)r * HW] = acc[m][nt][r] * s;
            }
        }
}

extern "C" void kernel_launch(void* const* d_in, const int* in_sizes, int n_in,
                              void* d_out, int out_size, void* d_ws, size_t ws_size,
                              hipStream_t stream) {
    const float* x   = (const float*)d_in[0];
    const float* p2  = (const float*)d_in[1];
    const float* p3  = (const float*)d_in[2];
    const float* p5  = (const float*)d_in[3];
    const float* p10 = (const float*)d_in[4];
    float* out = (float*)d_out;

    uint8_t* w8 = (uint8_t*)d_ws;
    uint16_t* t3b  = (uint16_t*)(w8);                 // 29,360,128 B (live to end)
    uint16_t* ap   = (uint16_t*)(w8 + 29360128);      //     98,304 B
    uint16_t* xtp  = (uint16_t*)(w8 + 29458432);      // 29,360,128 B (live to end)
    float*    part = (float*)   (w8 + 58818560);      // 44,040,192 B (dead after kr)
    uint16_t* p10t = (uint16_t*)(w8 + 58818560);      //  2,752,512 B (aliases dead part)
    uint16_t* acat = (uint16_t*)(w8 + 102858752);     //  4,194,304 B (end 107,053,056)

    p1_xtp<<<dim3(H_, NB), 256, 0, stream>>>(x, xtp);
    p2_ap<<<dim3(192), 256, 0, stream>>>(p3, ap);
    k1<<<dim3(H_, NB), 256, 0, stream>>>(xtp, ap, t3b);
    k2<<<dim3(21, NB), 512, 0, stream>>>(x, t3b, part);
    kr<<<dim3(1536), 256, 0, stream>>>(part, acat);
    ka2<<<dim3(128), 256, 0, stream>>>(acat);
    kt<<<dim3(H_), 256, 0, stream>>>(p10, p10t);      // after kr: part is dead
    k3<<<dim3(H_, NB), 256, 0, stream>>>(xtp, t3b, acat, p10t, p2, p5, out);
}

// Round 8
// 249.107 us; speedup vs baseline: 1.3807x; 1.0519x over previous
//
#include <hip/hip_runtime.h>
#include <stdint.h>

#define NB 32
#define C_ 128
#define H_ 56
#define W_ 56
#define HW 3136
#define KD 384

typedef __attribute__((ext_vector_type(8))) short bf16x8;
typedef __attribute__((ext_vector_type(4))) float f32x4;

__device__ inline uint16_t f2bf(float f) {
    uint32_t u = __float_as_uint(f);
    return (uint16_t)((u + 0x7FFFu + ((u >> 16) & 1u)) >> 16);
}
__device__ inline float bf2f(uint16_t b) {
    return __uint_as_float(((uint32_t)b) << 16);
}

// ---------------------------------------------------------------------------
// P1: x (f32) -> xtp bf16 [n][h][w(64,pad0)][c]
// ---------------------------------------------------------------------------
__global__ __launch_bounds__(256) void p1_xtp(const float* __restrict__ x,
                                              uint16_t* __restrict__ xtp) {
    __shared__ uint16_t lt[56][136];
    const int h = blockIdx.x, n = blockIdx.y, tid = threadIdx.x;
    const int c = tid >> 1, wh = tid & 1;
    const float* xr = &x[(((size_t)n * C_ + c) * H_ + h) * W_ + wh * 28];
#pragma unroll
    for (int q = 0; q < 7; ++q) {
        float4 v = *(const float4*)&xr[q * 4];
        int wb = wh * 28 + q * 4;
        lt[wb + 0][c] = f2bf(v.x);
        lt[wb + 1][c] = f2bf(v.y);
        lt[wb + 2][c] = f2bf(v.z);
        lt[wb + 3][c] = f2bf(v.w);
    }
    __syncthreads();
    const int w = tid >> 2, qc = tid & 3;
    uint16_t* dst = &xtp[((((size_t)n * H_ + h) * 64 + w)) * C_ + qc * 32];
    if (w < 56) {
        const uint32_t* s = (const uint32_t*)&lt[w][qc * 32];
        uint4 a = *(const uint4*)(s);
        uint4 b = *(const uint4*)(s + 4);
        uint4 c4 = *(const uint4*)(s + 8);
        uint4 d4 = *(const uint4*)(s + 12);
        *(uint4*)dst = a;
        *(uint4*)(dst + 8) = b;
        *(uint4*)(dst + 16) = c4;
        *(uint4*)(dst + 24) = d4;
    } else {
        uint4 z = {0, 0, 0, 0};
        *(uint4*)dst = z;
        *(uint4*)(dst + 8) = z;
        *(uint4*)(dst + 16) = z;
        *(uint4*)(dst + 24) = z;
    }
}

// ---------------------------------------------------------------------------
// P2: p3 -> ap bf16 [c][d'=tap*128+c2]
// ---------------------------------------------------------------------------
__global__ __launch_bounds__(256) void p2_ap(const float* __restrict__ p3,
                                             uint16_t* __restrict__ ap) {
    int i = blockIdx.x * 256 + threadIdx.x;
    int c = i / KD, dp = i - c * KD;
    int tap = dp >> 7, c2 = dp & 127;
    ap[i] = f2bf(p3[c * KD + 3 * c2 + tap]);
}

// ---------------------------------------------------------------------------
// K1: MFMA -> t3b[n][c][h][w64]
// ---------------------------------------------------------------------------
__global__ __launch_bounds__(256) void k1(const uint16_t* __restrict__ xtp,
                                          const uint16_t* __restrict__ ap,
                                          uint16_t* __restrict__ t3b) {
    __shared__ uint16_t smem[3 * 64 * 128];
    const int h = blockIdx.x, n = blockIdx.y, tid = threadIdx.x;
    const int lane = tid & 63, wid = tid >> 6;
    const int wm = wid >> 1, wn = wid & 1;

    for (int t = tid; t < 3072; t += 256) {
        int tap = t >> 10, r = t & 1023, w = r >> 4, qp = r & 15;
        int q = qp ^ (w & 7);
        int hh = h + 2 * (tap - 1);
        uint4 v = {0, 0, 0, 0};
        if ((unsigned)hh < (unsigned)H_)
            v = *(const uint4*)&xtp[((((size_t)n * H_ + hh) * 64 + w)) * C_ + q * 8];
        *(uint4*)&smem[tap * 8192 + w * 128 + qp * 8] = v;
    }
    __syncthreads();

    f32x4 acc[4][2] = {};
    for (int ks = 0; ks < 12; ++ks) {
        int tap = ks >> 2, kk = ks & 3;
        bf16x8 a[4], b[2];
#pragma unroll
        for (int m = 0; m < 4; ++m) {
            int c = wm * 64 + m * 16 + (lane & 15);
            a[m] = *(const bf16x8*)&ap[c * KD + ks * 32 + (lane >> 4) * 8];
        }
#pragma unroll
        for (int nt = 0; nt < 2; ++nt) {
            int w = wn * 32 + nt * 16 + (lane & 15);
            int q = kk * 4 + (lane >> 4);
            b[nt] = *(const bf16x8*)&smem[tap * 8192 + w * 128 + (q ^ (w & 7)) * 8];
        }
#pragma unroll
        for (int m = 0; m < 4; ++m)
#pragma unroll
            for (int nt = 0; nt < 2; ++nt)
                acc[m][nt] = __builtin_amdgcn_mfma_f32_16x16x32_bf16(a[m], b[nt], acc[m][nt], 0, 0, 0);
    }
    __syncthreads();

    uint16_t* lrow = smem;
#pragma unroll
    for (int m = 0; m < 4; ++m)
#pragma unroll
        for (int nt = 0; nt < 2; ++nt)
#pragma unroll
            for (int r = 0; r < 4; ++r) {
                int c = wm * 64 + m * 16 + (lane >> 4) * 4 + r;
                int w = wn * 32 + nt * 16 + (lane & 15);
                lrow[c * 72 + w] = f2bf(acc[m][nt][r]);
            }
    __syncthreads();

    const uint32_t* lrowd = (const uint32_t*)smem;
    for (int t = tid; t < 1024; t += 256) {
        int c = t >> 3, ch = t & 7;
        int m0 = c * 36 + ch * 4;
        uint4 o = make_uint4(lrowd[m0], lrowd[m0 + 1], lrowd[m0 + 2], lrowd[m0 + 3]);
        *(uint4*)&t3b[(((size_t)n * C_ + c) * H_ + h) * 64 + ch * 8] = o;
    }
}

// ---------------------------------------------------------------------------
// K2: part[bx][n][c][c2] partial t9 (plain stores, reduced in kr)
// ---------------------------------------------------------------------------
__global__ __launch_bounds__(512) void k2(const float* __restrict__ x,
                                          const uint16_t* __restrict__ t3b,
                                          float* __restrict__ part) {
    __shared__ uint16_t xs[128 * 64];
    __shared__ uint16_t ts[128 * 64];
    const int bx = blockIdx.x;
    const int hc = bx / 3, tap = bx - hc * 3;
    const int n = blockIdx.y;
    const int tid = threadIdx.x, lane = tid & 63, wid = tid >> 6;
    const int wm = wid >> 2, wn = wid & 3;

    f32x4 acc[4][2] = {};
    for (int hr = 0; hr < 8; ++hr) {
        const int h = hc * 8 + hr;
        __syncthreads();
        for (int t = tid; t < 1024; t += 512) {
            int c = t >> 3, qp = t & 7, q = qp ^ (c & 7);
            uint4 v = {0, 0, 0, 0};
            if (q < 7) {
                const float* s = &x[(((size_t)n * C_ + c) * H_ + h) * W_ + q * 8];
                float4 f0 = *(const float4*)s, f1 = *(const float4*)(s + 4);
                v.x = (uint32_t)f2bf(f0.x) | ((uint32_t)f2bf(f0.y) << 16);
                v.y = (uint32_t)f2bf(f0.z) | ((uint32_t)f2bf(f0.w) << 16);
                v.z = (uint32_t)f2bf(f1.x) | ((uint32_t)f2bf(f1.y) << 16);
                v.w = (uint32_t)f2bf(f1.z) | ((uint32_t)f2bf(f1.w) << 16);
            }
            *(uint4*)&xs[c * 64 + qp * 8] = v;
        }
        for (int t = tid; t < 1024; t += 512) {
            int c2 = t >> 3, qp = t & 7, q = qp ^ (c2 & 7);
            const uint16_t* row = &t3b[(((size_t)n * C_ + c2) * H_ + h) * 64];
            uint4 v = *(const uint4*)&row[q * 8];
            uint4 o;
            if (tap == 1) {
                o = v;
            } else if (tap == 2) {
                uint32_t nx = (q < 7) ? *(const uint32_t*)&row[q * 8 + 8] : 0u;
                o.x = (v.y << 16) | (v.x >> 16);
                o.y = (v.z << 16) | (v.y >> 16);
                o.z = (v.w << 16) | (v.z >> 16);
                o.w = (nx << 16)  | (v.w >> 16);
            } else {
                uint32_t pv = (q > 0) ? *(const uint32_t*)&row[q * 8 - 2] : 0u;
                o.x = (v.x << 16) | (pv >> 16);
                o.y = (v.y << 16) | (v.x >> 16);
                o.z = (v.z << 16) | (v.y >> 16);
                o.w = (v.w << 16) | (v.z >> 16);
            }
            *(uint4*)&ts[c2 * 64 + qp * 8] = o;
        }
        __syncthreads();
#pragma unroll
        for (int ks = 0; ks < 2; ++ks) {
            bf16x8 a[4], b[2];
#pragma unroll
            for (int m = 0; m < 4; ++m) {
                int c = wm * 64 + m * 16 + (lane & 15);
                int q = ks * 4 + (lane >> 4);
                a[m] = *(const bf16x8*)&xs[c * 64 + (q ^ (c & 7)) * 8];
            }
#pragma unroll
            for (int nt = 0; nt < 2; ++nt) {
                int c2 = wn * 32 + nt * 16 + (lane & 15);
                int q = ks * 4 + (lane >> 4);
                b[nt] = *(const bf16x8*)&ts[c2 * 64 + (q ^ (c2 & 7)) * 8];
            }
#pragma unroll
            for (int m = 0; m < 4; ++m)
#pragma unroll
                for (int nt = 0; nt < 2; ++nt)
                    acc[m][nt] = __builtin_amdgcn_mfma_f32_16x16x32_bf16(a[m], b[nt], acc[m][nt], 0, 0, 0);
        }
    }
#pragma unroll
    for (int m = 0; m < 4; ++m)
#pragma unroll
        for (int nt = 0; nt < 2; ++nt)
#pragma unroll
            for (int r = 0; r < 4; ++r) {
                int c = wm * 64 + m * 16 + (lane >> 4) * 4 + r;
                int col = wn * 32 + nt * 16 + (lane & 15);
                part[((((size_t)bx * NB + n) * C_ + c) << 7) + col] = acc[m][nt][r];
            }
}

// ---------------------------------------------------------------------------
// R: acat[n][c][dp<384] = bf16( (1/56) * sum_hc part )   (row stride 512)
// ---------------------------------------------------------------------------
__global__ __launch_bounds__(256) void kr(const float* __restrict__ part,
                                          uint16_t* __restrict__ acat) {
    int idx = blockIdx.x * 256 + threadIdx.x;
    int fl = idx * 4;
    int nc = fl / KD, dp = fl - nc * KD;
    int tap = dp >> 7, c2 = dp & 127;
    float4 s = make_float4(0.f, 0.f, 0.f, 0.f);
#pragma unroll
    for (int hc = 0; hc < 7; ++hc) {
        const float4 v = *(const float4*)&part[((((size_t)(hc * 3 + tap)) * NB * C_ + nc) << 7) + c2];
        s.x += v.x; s.y += v.y; s.z += v.z; s.w += v.w;
    }
    const float sc = 1.f / 56.f;
    uint2 o;
    o.x = (uint32_t)f2bf(s.x * sc) | ((uint32_t)f2bf(s.y * sc) << 16);
    o.y = (uint32_t)f2bf(s.z * sc) | ((uint32_t)f2bf(s.w * sc) << 16);
    *(uint2*)&acat[(size_t)nc * 512 + dp] = o;
}

// ---------------------------------------------------------------------------
// KA2: acat[nc][384+m] = sum_{r=0..2} acat[nc][dp(m+128r)], dp(d)=(d%3)*128+d/3
// ---------------------------------------------------------------------------
__global__ __launch_bounds__(256) void ka2(uint16_t* __restrict__ acat) {
    int t = blockIdx.x * 256 + threadIdx.x;
    int nc = t >> 3, m0 = (t & 7) * 16;
    uint16_t* row = &acat[(size_t)nc * 512];
#pragma unroll
    for (int mi = 0; mi < 16; ++mi) {
        int m = m0 + mi;
        float s = 0.f;
#pragma unroll
        for (int r = 0; r < 3; ++r) {
            int d = m + 128 * r;
            int q3 = d / 3;
            int dp = (d - q3 * 3) * 128 + q3;
            s += bf2f(row[dp]);
        }
        row[384 + m] = f2bf(s);
    }
}

// ---------------------------------------------------------------------------
// KT: p10 -> p10t bf16 [h][w64][d'=tap*128+c2]; rows w>=56 zero
// ---------------------------------------------------------------------------
__global__ __launch_bounds__(256) void kt(const float* __restrict__ p10,
                                          uint16_t* __restrict__ p10t) {
    const int h = blockIdx.x, tid = threadIdx.x;
    for (int idx = tid; idx < 3072; idx += 256) {
        int w = idx & 63, ch = idx >> 6;
        int dp0 = ch * 8;
        uint32_t pk[4];
#pragma unroll
        for (int j = 0; j < 8; ++j) {
            int dp = dp0 + j;
            int tap = dp >> 7, c2 = dp & 127;
            int dor = 3 * c2 + tap;
            float v = (w < W_) ? p10[(size_t)dor * HW + h * W_ + w] : 0.f;
            uint16_t bb = f2bf(v);
            if (j & 1) pk[j >> 1] |= ((uint32_t)bb) << 16;
            else       pk[j >> 1] = bb;
        }
        *(uint4*)&p10t[((size_t)h * 64 + w) * KD + dp0] = *(const uint4*)pk;
    }
}

// ---------------------------------------------------------------------------
// K3: K=512 GEMM, N-split: each block owns 32 w-cols -> 32KB LDS, 5 blocks/CU.
// B rows 0..383 = -(p2*x + p10*sm); rows 384..511 = p5*t3. A = acat.
// grid (112 = h*2+wb fast, n slow) so 112 consecutive blocks share n in L2.
// ---------------------------------------------------------------------------
__global__ __launch_bounds__(256, 4) void k3(const uint16_t* __restrict__ xtp,
                                             const uint16_t* __restrict__ t3b,
                                             const uint16_t* __restrict__ acat,
                                             const uint16_t* __restrict__ p10t,
                                             const float* __restrict__ p2,
                                             const float* __restrict__ p5,
                                             float* __restrict__ out) {
    __shared__ uint16_t tsm[32 * 512];  // 32 KB, rows w-local (1024B), XOR-swz
    const int bx = blockIdx.x, n = blockIdx.y, tid = threadIdx.x;
    const int h = bx >> 1, wbase = (bx & 1) << 5;
    const int lane = tid & 63, wid = tid >> 6;

    // ---- build rows 0..383: thread = (w-local 0..31, seg 0..7) ----
    {
        const int w = tid & 31, seg = tid >> 5;
        const int wg = wbase + w;
        const int wsw = w & 7;
        float p2v[3];
#pragma unroll
        for (int tap = 0; tap < 3; ++tap)
            p2v[tap] = (wg < W_) ? p2[tap * W_ + wg] : 0.f;
        const size_t xrow = ((size_t)n * H_ + h) * 64;
        const int wgm2 = (wg >= 2) ? wg - 2 : 0;
        const int wgp2 = (wg + 2 < 64) ? wg + 2 : 63;   // rows >=56 are zeros

#pragma unroll
        for (int s = 0; s < 2; ++s) {
            const int c2b = (seg + s * 8) * 8;
            bf16x8 xh_v = *(const bf16x8*)&xtp[(xrow + wg) * C_ + c2b];
            bf16x8 xm_v = *(const bf16x8*)&xtp[(xrow + wgm2) * C_ + c2b];
            bf16x8 xp_v = *(const bf16x8*)&xtp[(xrow + wgp2) * C_ + c2b];
            float sm[3][8];
#pragma unroll
            for (int j = 0; j < 8; ++j) {
                float a1 = bf2f((uint16_t)xh_v[j]);
                float a0 = (wg >= 2) ? bf2f((uint16_t)xm_v[j]) : 0.f;
                float a2 = bf2f((uint16_t)xp_v[j]);
                float mx = fmaxf(a0, fmaxf(a1, a2));
                float e0 = __expf(a0 - mx), e1 = __expf(a1 - mx), e2 = __expf(a2 - mx);
                float rs = 1.f / (e0 + e1 + e2);
                sm[0][j] = e0 * rs; sm[1][j] = e1 * rs; sm[2][j] = e2 * rs;
            }
#pragma unroll
            for (int tap = 0; tap < 3; ++tap) {
                bf16x8 xhh;
                float p2e;
                if (tap == 1) { xhh = xh_v; p2e = p2v[1]; }
                else {
                    const int hh = h + 2 * (tap - 1);
                    const bool hok = (unsigned)hh < (unsigned)H_;
                    const int hhc = hok ? hh : h;
                    xhh = *(const bf16x8*)&xtp[(((size_t)n * H_ + hhc) * 64 + wg) * C_ + c2b];
                    p2e = hok ? p2v[tap] : 0.f;
                }
                bf16x8 pv = *(const bf16x8*)&p10t[((size_t)h * 64 + wg) * KD + tap * 128 + c2b];
                uint32_t pk[4];
#pragma unroll
                for (int j = 0; j < 8; ++j) {
                    float val = -(p2e * bf2f((uint16_t)xhh[j]) + bf2f((uint16_t)pv[j]) * sm[tap][j]);
                    uint16_t bb = f2bf(val);
                    if (j & 1) pk[j >> 1] |= ((uint32_t)bb) << 16;
                    else       pk[j >> 1] = bb;
                }
                int q = (tap * 128 + c2b) >> 3;   // 0..47
                *(uint4*)&tsm[w * 512 + ((q ^ wsw) << 3)] = *(const uint4*)pk;
            }
        }
    }

    // ---- rows 384..511: p5*t3; thread = (c2f 0..127, w-half 0..1) ----
    {
        const int c2f = tid >> 1;
        const int whl = (tid & 1) << 4;    // local w 0..15 / 16..31
        const uint16_t* t3r = &t3b[(((size_t)n * C_ + c2f) * H_ + h) * 64 + wbase + whl];
        const int qf = 48 + (c2f >> 3);
        const int cf7 = c2f & 7;
#pragma unroll
        for (int g = 0; g < 2; ++g) {
            bf16x8 tv = *(const bf16x8*)&t3r[g * 8];
#pragma unroll
            for (int j = 0; j < 8; ++j) {
                int wl = whl + g * 8 + j;
                int wwg = wbase + wl;
                float p5v = (wwg < W_) ? p5[h * W_ + wwg] : 0.f;
                tsm[wl * 512 + ((qf ^ (wl & 7)) << 3) + cf7] = f2bf(p5v * bf2f((uint16_t)tv[j]));
            }
        }
    }
    __syncthreads();

    // ---- 16-kstep GEMM: wave wm owns c-band [wm*32, wm*32+32) ----
    const int wm = wid;
    f32x4 acc[2][2] = {};
    for (int ks = 0; ks < 16; ++ks) {
        bf16x8 a[2], b[2];
#pragma unroll
        for (int m = 0; m < 2; ++m) {
            int c = wm * 32 + m * 16 + (lane & 15);
            a[m] = *(const bf16x8*)&acat[((size_t)n * C_ + c) * 512 + ks * 32 + (lane >> 4) * 8];
        }
#pragma unroll
        for (int nt = 0; nt < 2; ++nt) {
            int wl = nt * 16 + (lane & 15);
            int q = ks * 4 + (lane >> 4);
            b[nt] = *(const bf16x8*)&tsm[wl * 512 + ((q ^ (wl & 7)) << 3)];
        }
#pragma unroll
        for (int m = 0; m < 2; ++m)
#pragma unroll
            for (int nt = 0; nt < 2; ++nt)
                acc[m][nt] = __builtin_amdgcn_mfma_f32_16x16x32_bf16(a[m], b[nt], acc[m][nt], 0, 0, 0);
    }

    const float s = 0.05103103630798287f;  // 1/sqrt(384)
#pragma unroll
    for (int m = 0; m < 2; ++m)
#pragma unroll
        for (int nt = 0; nt < 2; ++nt) {
            int wwg = wbase + nt * 16 + (lane & 15);
            if (wwg < W_) {
                int c = wm * 32 + m * 16 + (lane >> 4) * 4;
                float* dst = &out[(((size_t)n * C_ + c) * H_ + h) * W_ + wwg];
#pragma unroll
                for (int r = 0; r < 4; ++r) dst[(size_t)r * HW] = acc[m][nt][r] * s;
            }
        }
}

extern "C" void kernel_launch(void* const* d_in, const int* in_sizes, int n_in,
                              void* d_out, int out_size, void* d_ws, size_t ws_size,
                              hipStream_t stream) {
    const float* x   = (const float*)d_in[0];
    const float* p2  = (const float*)d_in[1];
    const float* p3  = (const float*)d_in[2];
    const float* p5  = (const float*)d_in[3];
    const float* p10 = (const float*)d_in[4];
    float* out = (float*)d_out;

    uint8_t* w8 = (uint8_t*)d_ws;
    uint16_t* t3b  = (uint16_t*)(w8);                 // 29,360,128 B (live to end)
    uint16_t* ap   = (uint16_t*)(w8 + 29360128);      //     98,304 B
    uint16_t* xtp  = (uint16_t*)(w8 + 29458432);      // 29,360,128 B (live to end)
    float*    part = (float*)   (w8 + 58818560);      // 44,040,192 B (dead after kr)
    uint16_t* p10t = (uint16_t*)(w8 + 58818560);      //  2,752,512 B (aliases dead part)
    uint16_t* acat = (uint16_t*)(w8 + 102858752);     //  4,194,304 B (end 107,053,056)

    p1_xtp<<<dim3(H_, NB), 256, 0, stream>>>(x, xtp);
    p2_ap<<<dim3(192), 256, 0, stream>>>(p3, ap);
    k1<<<dim3(H_, NB), 256, 0, stream>>>(xtp, ap, t3b);
    k2<<<dim3(21, NB), 512, 0, stream>>>(x, t3b, part);
    kr<<<dim3(1536), 256, 0, stream>>>(part, acat);
    ka2<<<dim3(128), 256, 0, stream>>>(acat);
    kt<<<dim3(H_), 256, 0, stream>>>(p10, p10t);      // after kr: part is dead
    k3<<<dim3(112, NB), 256, 0, stream>>>(xtp, t3b, acat, p10t, p2, p5, out);
}